// Round 5
// baseline (384.009 us; speedup 1.0000x reference)
//
#include <hip/hip_runtime.h>

#define B_ 16
#define S_ 20
#define L_ 64
#define T_ 1280
#define H_ 768
#define NITEMS 50000
#define TEMP 0.05f
#define EPSN 1e-8f

#define MT 80    // m-rows per block (mt tile)
#define NKT 24   // K steps of 32

typedef __attribute__((ext_vector_type(8))) short short8;
typedef __attribute__((ext_vector_type(4))) short short4v;
typedef __attribute__((ext_vector_type(4))) float f32x4;

union U16x4 { uint4 u; short8 s; };

// full RNE float->bf16 (pool)
__device__ __forceinline__ unsigned short f2bf(float f) {
    unsigned int u = __float_as_uint(f);
    u = u + 0x7FFFu + ((u >> 16) & 1u);
    return (unsigned short)(u >> 16);
}

// pack two floats -> two bf16 (round-half-up), 3 VALU for 2 elems
__device__ __forceinline__ unsigned int pack_bf16(float f0, float f1) {
    const unsigned int u0 = __float_as_uint(f0) + 0x8000u;
    const unsigned int u1 = __float_as_uint(f1) + 0x8000u;
    return __builtin_amdgcn_perm(u1, u0, 0x07060302u);
}

// ---------------------------------------------------------------------------
// Kernel 1: per-(b,s) nan-mean pool, normalize, fold 1/(pn*TEMP), write bf16.
// ---------------------------------------------------------------------------
__global__ __launch_bounds__(192) void pool_kernel(const float* __restrict__ hidden,
                                                   const int* __restrict__ pos,
                                                   unsigned short* __restrict__ A,
                                                   int* __restrict__ valid) {
    const int row = blockIdx.x;  // 0..319
    const int b = row / S_, s = row % S_;
    const int tid = threadIdx.x;  // owns 4 consecutive h-cols

    __shared__ float wgt[L_];
    __shared__ int cntS;
    __shared__ float red[3];

    const int* pbase = pos + b * T_ + s * L_;
    if (tid < L_) {
        const int match = (pbase[tid] == s + 1) ? 1 : 0;
        unsigned long long bal = __ballot(match);
        wgt[tid] = match ? 1.0f : 0.0f;
        if (tid == 0) cntS = (int)__popcll(bal);
    }
    __syncthreads();

    const int cnt = cntS;
    const float inv = 1.0f / (float)(cnt > 0 ? cnt : 1);
    const float* hbase = hidden + ((size_t)b * T_ + (size_t)s * L_) * H_ + tid * 4;

    float a0 = 0.f, a1 = 0.f, a2 = 0.f, a3 = 0.f;
#pragma unroll 8
    for (int t = 0; t < L_; ++t) {
        const float w = wgt[t];
        const float4 v = *reinterpret_cast<const float4*>(hbase + (size_t)t * H_);
        a0 += w * v.x; a1 += w * v.y; a2 += w * v.z; a3 += w * v.w;
    }
    a0 *= inv; a1 *= inv; a2 *= inv; a3 *= inv;

    float ss = a0 * a0 + a1 * a1 + a2 * a2 + a3 * a3;
#pragma unroll
    for (int off = 32; off; off >>= 1) ss += __shfl_xor(ss, off, 64);
    const int wave = tid >> 6, lane = tid & 63;
    if (lane == 0) red[wave] = ss;
    __syncthreads();
    const float tot = red[0] + red[1] + red[2];
    const float scale = 1.0f / (fmaxf(sqrtf(tot), EPSN) * TEMP);

    short4v w4;
    w4[0] = (short)f2bf(a0 * scale);
    w4[1] = (short)f2bf(a1 * scale);
    w4[2] = (short)f2bf(a2 * scale);
    w4[3] = (short)f2bf(a3 * scale);
    *reinterpret_cast<short4v*>(A + (size_t)row * H_ + tid * 4) = w4;
    if (tid == 0) valid[row] = (cnt > 0) ? 1 : 0;
}

// ---------------------------------------------------------------------------
// Kernel 2: no-LDS streaming GEMM, zero K-loop barriers.
// Grid: 1568 blocks = 392 nt x 4 mt, swizzled so the 4 same-nt blocks share
// bid&7 (-> same XCD -> one L2 fill per emb row). Block = 4 waves; wave owns
// 80 m-rows x 32 n-cols, full K. Per kt: 5 A-frag loads (global, L2-resident
// 480KB) + 4 B loads (fp32 emb), register double-buffered ahead of the 10
// MFMAs -> deep per-wave vmcnt pipeline, no collective drains. en in-reg.
// ---------------------------------------------------------------------------
__global__ __launch_bounds__(256, 3) void gemm_kernel(const float* __restrict__ emb,
                                                      const unsigned short* __restrict__ A,
                                                      const int* __restrict__ valid,
                                                      float* __restrict__ out) {
    const int bid = blockIdx.x;
    const int ring = bid >> 3, l8 = bid & 7;
    const int nt = (ring >> 2) * 8 + l8;  // 0..391 (nt=391 fully OOB, stores guarded)
    const int mt = ring & 3;              // same-nt group shares bid&7 -> same XCD
    const int tid = threadIdx.x;
    const int wave = tid >> 6, lane = tid & 63, quad = lane >> 4, lq = lane & 15;

    __shared__ int sMask[4];
    if (tid < 4) {
        int m = 0;
        for (int s = 0; s < S_; ++s) m |= (valid[(mt * 4 + tid) * S_ + s] ? 1 : 0) << s;
        sMask[tid] = m;
    }
    __syncthreads();  // only barrier; nothing in flight yet

    // B row pointers (clamped; clamped cols never stored)
    const int n0w = nt * 128 + wave * 32;
    int r0 = n0w + lq;       if (r0 > NITEMS - 1) r0 = NITEMS - 1;
    int r1 = n0w + 16 + lq;  if (r1 > NITEMS - 1) r1 = NITEMS - 1;
    const float* bp0 = emb + (size_t)r0 * H_ + quad * 8;
    const float* bp1 = emb + (size_t)r1 * H_ + quad * 8;
    // A-frag base: row mt*80 + mf*16 + lq, col quad*8 (+ kt*32)
    const unsigned short* ap = A + (size_t)(mt * MT + lq) * H_ + quad * 8;

    uint4 aP[2][5];
    float4 bP[2][4];

#define PREFETCH(kt, slot)                                                        \
    do {                                                                          \
        const int ko = (kt) * 32;                                                 \
        _Pragma("unroll") for (int mf = 0; mf < 5; ++mf)                          \
            aP[slot][mf] = *reinterpret_cast<const uint4*>(ap + mf * 16 * H_ + ko); \
        bP[slot][0] = *reinterpret_cast<const float4*>(bp0 + ko);                 \
        bP[slot][1] = *reinterpret_cast<const float4*>(bp0 + ko + 4);             \
        bP[slot][2] = *reinterpret_cast<const float4*>(bp1 + ko);                 \
        bP[slot][3] = *reinterpret_cast<const float4*>(bp1 + ko + 4);             \
    } while (0)

    PREFETCH(0, 0);

    float rowSq0 = 0.f, rowSq1 = 0.f;
    f32x4 acc[5][2];
#pragma unroll
    for (int i = 0; i < 5; ++i) {
        acc[i][0] = (f32x4)0.f;
        acc[i][1] = (f32x4)0.f;
    }

#pragma unroll 2
    for (int kt = 0; kt < NKT; ++kt) {
        const int cur = kt & 1;
        if (kt + 1 < NKT) PREFETCH(kt + 1, cur ^ 1);

        const float4 x0 = bP[cur][0], y0 = bP[cur][1];
        const float4 x1 = bP[cur][2], y1 = bP[cur][3];

        rowSq0 += x0.x * x0.x + x0.y * x0.y + x0.z * x0.z + x0.w * x0.w
                + y0.x * y0.x + y0.y * y0.y + y0.z * y0.z + y0.w * y0.w;
        rowSq1 += x1.x * x1.x + x1.y * x1.y + x1.z * x1.z + x1.w * x1.w
                + y1.x * y1.x + y1.y * y1.y + y1.z * y1.z + y1.w * y1.w;

        U16x4 bF0, bF1;
        bF0.u.x = pack_bf16(x0.x, x0.y); bF0.u.y = pack_bf16(x0.z, x0.w);
        bF0.u.z = pack_bf16(y0.x, y0.y); bF0.u.w = pack_bf16(y0.z, y0.w);
        bF1.u.x = pack_bf16(x1.x, x1.y); bF1.u.y = pack_bf16(x1.z, x1.w);
        bF1.u.z = pack_bf16(y1.x, y1.y); bF1.u.w = pack_bf16(y1.z, y1.w);

#pragma unroll
        for (int mf = 0; mf < 5; ++mf) {
            U16x4 aF; aF.u = aP[cur][mf];
            acc[mf][0] = __builtin_amdgcn_mfma_f32_16x16x32_bf16(aF.s, bF0.s, acc[mf][0], 0, 0, 0);
            acc[mf][1] = __builtin_amdgcn_mfma_f32_16x16x32_bf16(aF.s, bF1.s, acc[mf][1], 0, 0, 0);
        }
    }
#undef PREFETCH

    // en: sum rowSq across the 4 quads (disjoint k-slices)
    rowSq0 += __shfl_xor(rowSq0, 16, 64);
    rowSq0 += __shfl_xor(rowSq0, 32, 64);
    rowSq1 += __shfl_xor(rowSq1, 16, 64);
    rowSq1 += __shfl_xor(rowSq1, 32, 64);
    float invEn[2];
    invEn[0] = 1.0f / fmaxf(sqrtf(rowSq0), EPSN);
    invEn[1] = 1.0f / fmaxf(sqrtf(rowSq1), EPSN);

    // epilogue: per-session masked max, /en, store
#pragma unroll
    for (int nf = 0; nf < 2; ++nf) {
        const int n = n0w + nf * 16 + lq;
        const float inv_en = invEn[nf];
#pragma unroll
        for (int bb = 0; bb < 4; ++bb) {
            const int rLo = bb * S_;
            const int msk = sMask[bb];
            const int mfLo = rLo >> 4;
            const int mfHi = (rLo + S_ - 1) >> 4;
            float lm = -__builtin_inff();
#pragma unroll
            for (int mf = mfLo; mf <= mfHi; ++mf)
#pragma unroll
                for (int e = 0; e < 4; ++e) {
                    const int r = mf * 16 + quad * 4 + e;  // C/D: row=quad*4+e
                    const unsigned off = (unsigned)(r - rLo);
                    const bool ok = (off < (unsigned)S_) && ((msk >> off) & 1);
                    lm = ok ? fmaxf(lm, acc[mf][nf][e]) : lm;
                }
            lm = fmaxf(lm, __shfl_xor(lm, 16, 64));
            lm = fmaxf(lm, __shfl_xor(lm, 32, 64));
            if (quad == 0 && n < NITEMS)
                out[(size_t)(mt * 4 + bb) * NITEMS + n] = lm * inv_en;
        }
    }
}

extern "C" void kernel_launch(void* const* d_in, const int* in_sizes, int n_in,
                              void* d_out, int out_size, void* d_ws, size_t ws_size,
                              hipStream_t stream) {
    const float* hidden = (const float*)d_in[0];   // [16,1280,768] f32
    const float* emb    = (const float*)d_in[1];   // [50000,768] f32
    const int*   pos    = (const int*)d_in[3];     // [16,1280] i32
    float* out = (float*)d_out;                    // [16,50000] f32

    unsigned short* Abf = (unsigned short*)d_ws;               // 320*768 bf16
    int* valid = (int*)((char*)d_ws + (size_t)320 * 768 * 2);  // 320 ints

    pool_kernel<<<dim3(320), dim3(192), 0, stream>>>(hidden, pos, Abf, valid);
    gemm_kernel<<<dim3(1568), dim3(256), 0, stream>>>(emb, Abf, valid, out);
}

// Round 7
// 312.055 us; speedup vs baseline: 1.2306x; 1.2306x over previous
//
#include <hip/hip_runtime.h>

#define B_ 16
#define S_ 20
#define L_ 64
#define T_ 1280
#define H_ 768
#define NITEMS 50000
#define TEMP 0.05f
#define EPSN 1e-8f

#define BN 48          // emb rows per block (full K staged in LDS)
#define RSTRIDE 776    // LDS row stride in bf16 elems (768+8 -> lq-lanes hit 2-way banks only)
#define NKT 24         // K steps of 32

typedef __attribute__((ext_vector_type(8))) short short8;
typedef __attribute__((ext_vector_type(4))) short short4v;
typedef __attribute__((ext_vector_type(4))) float f32x4;

union U16x4 { uint4 u; short8 s; };

// full RNE float->bf16 (pool)
__device__ __forceinline__ unsigned short f2bf(float f) {
    unsigned int u = __float_as_uint(f);
    u = u + 0x7FFFu + ((u >> 16) & 1u);
    return (unsigned short)(u >> 16);
}

// pack two floats -> two bf16 (round-half-up), 3 VALU per 2 elems
__device__ __forceinline__ unsigned int pack_bf16(float f0, float f1) {
    const unsigned int u0 = __float_as_uint(f0) + 0x8000u;
    const unsigned int u1 = __float_as_uint(f1) + 0x8000u;
    return __builtin_amdgcn_perm(u1, u0, 0x07060302u);
}

__device__ __forceinline__ float bf2f(unsigned short u) {
    return __uint_as_float(((unsigned int)u) << 16);
}

// ---------------------------------------------------------------------------
// Kernel 1: per-(b,s) nan-mean pool, normalize, fold 1/(pn*TEMP).
// Output written in MFMA-A-fragment-packed order:
//   Apack[r16][kt][lane=quad*16+lq][8]  (elem (row,k): r16=row/16, lq=row%16,
//   kt=k/32, quad=(k%32)/8, j=k%8)
// so the gemm's A-frag load is ONE coalesced 1KB global_load_dwordx4.
// ---------------------------------------------------------------------------
__global__ __launch_bounds__(192) void pool_kernel(const float* __restrict__ hidden,
                                                   const int* __restrict__ pos,
                                                   unsigned short* __restrict__ Apack,
                                                   int* __restrict__ valid) {
    const int row = blockIdx.x;  // 0..319
    const int b = row / S_, s = row % S_;
    const int r16 = row >> 4, lqr = row & 15;
    const int tid = threadIdx.x;  // owns k = tid*4 .. tid*4+3

    __shared__ float wgt[L_];
    __shared__ int cntS;
    __shared__ float red[3];

    const int* pbase = pos + b * T_ + s * L_;
    if (tid < L_) {
        const int match = (pbase[tid] == s + 1) ? 1 : 0;
        unsigned long long bal = __ballot(match);
        wgt[tid] = match ? 1.0f : 0.0f;
        if (tid == 0) cntS = (int)__popcll(bal);
    }
    __syncthreads();

    const int cnt = cntS;
    const float inv = 1.0f / (float)(cnt > 0 ? cnt : 1);
    const float* hbase = hidden + ((size_t)b * T_ + (size_t)s * L_) * H_ + tid * 4;

    float a0 = 0.f, a1 = 0.f, a2 = 0.f, a3 = 0.f;
#pragma unroll 8
    for (int t = 0; t < L_; ++t) {
        const float w = wgt[t];
        const float4 v = *reinterpret_cast<const float4*>(hbase + (size_t)t * H_);
        a0 += w * v.x; a1 += w * v.y; a2 += w * v.z; a3 += w * v.w;
    }
    a0 *= inv; a1 *= inv; a2 *= inv; a3 *= inv;

    float ss = a0 * a0 + a1 * a1 + a2 * a2 + a3 * a3;
#pragma unroll
    for (int off = 32; off; off >>= 1) ss += __shfl_xor(ss, off, 64);
    const int wv = tid >> 6, lane = tid & 63;
    if (lane == 0) red[wv] = ss;
    __syncthreads();
    const float tot = red[0] + red[1] + red[2];
    const float scale = 1.0f / (fmaxf(sqrtf(tot), EPSN) * TEMP);

    // packed write: k = tid*4 -> kt = tid/8, quad = (tid/2)&3, j0 = (tid&1)*4
    const int kt = tid >> 3, quad = (tid >> 1) & 3, j0 = (tid & 1) * 4;
    short4v w4;
    w4[0] = (short)f2bf(a0 * scale);
    w4[1] = (short)f2bf(a1 * scale);
    w4[2] = (short)f2bf(a2 * scale);
    w4[3] = (short)f2bf(a3 * scale);
    *reinterpret_cast<short4v*>(Apack + ((size_t)r16 * NKT + kt) * 512 +
                                (quad * 16 + lqr) * 8 + j0) = w4;
    if (tid == 0) valid[row] = (cnt > 0) ? 1 : 0;
}

// ---------------------------------------------------------------------------
// Kernel 2: GEMM with B full-K in LDS, barrier-free K-loop.
// Grid = 1042 n-tiles of 48 rows; block covers ALL 320 m-rows (emb read once).
// Block = 256 thr (4 waves); wave h owns m-rows [80h,80h+80) x all 48 n.
// Stage: 48x768 fp32 emb -> bf16 LDS (coalesced flat-index), barrier;
// en from staged bf16 tile, barrier; then 24 kt of {5 coalesced 1KB A-frag
// global loads (3-deep prefetch) + 3 ds_read_b128 B-frags (2-deep) + 15 MFMA}
// with NO barriers -> per-wave vmcnt pipelining; 2 blocks/CU overlap
// stage/compute phases.
// ---------------------------------------------------------------------------
__global__ __launch_bounds__(256, 2) void gemm_kernel(const float* __restrict__ emb,
                                                      const unsigned short* __restrict__ Apack,
                                                      const int* __restrict__ valid,
                                                      float* __restrict__ out) {
    const int nt = blockIdx.x;  // 0..1041
    const int n0 = nt * BN;
    const int tid = threadIdx.x;
    const int wave = tid >> 6, lane = tid & 63, quad = lane >> 4, lq = lane & 15;

    __shared__ alignas(16) short Bs[BN * RSTRIDE];  // 74,496 B
    __shared__ float sInvEn[BN];
    __shared__ int sMask[B_];

    if (tid < B_) {
        int m = 0;
        for (int s = 0; s < S_; ++s) m |= (valid[tid * S_ + s] ? 1 : 0) << s;
        sMask[tid] = m;
    }

    // ---- stage emb rows [n0, n0+48) fp32 -> bf16 LDS, fully coalesced ----
    // flat float4 index f = i*256 + tid over 48*192 = 9216 float4
#pragma unroll
    for (int i = 0; i < 36; ++i) {
        const int f = i * 256 + tid;
        const int row = (unsigned)f / 192u;
        const int c4 = f - row * 192;
        int gr = n0 + row; if (gr > NITEMS - 1) gr = NITEMS - 1;
        const float4 v = *reinterpret_cast<const float4*>(emb + (size_t)gr * H_ + c4 * 4);
        uint2 w;
        w.x = pack_bf16(v.x, v.y);
        w.y = pack_bf16(v.z, v.w);
        *reinterpret_cast<uint2*>(reinterpret_cast<char*>(Bs) + row * (RSTRIDE * 2) + c4 * 8) = w;
    }
    __syncthreads();

    // ---- en from the staged bf16 tile (norm err ~1e-4, negligible) ----
    // 4 threads/row, each owns 192 elems = 384 bytes = 24 x 16B reads
    if (tid < 192) {
        const int row = tid >> 2, sub = tid & 3;
        const char* rp = reinterpret_cast<const char*>(Bs) + row * (RSTRIDE * 2) + sub * 384;
        float ss = 0.f;
#pragma unroll
        for (int i = 0; i < 24; ++i) {
            const short8 v = *reinterpret_cast<const short8*>(rp + i * 16);
#pragma unroll
            for (int j = 0; j < 8; ++j) {
                const float x = bf2f((unsigned short)v[j]);
                ss += x * x;
            }
        }
        ss += __shfl_xor(ss, 1, 64);
        ss += __shfl_xor(ss, 2, 64);
        if (sub == 0) sInvEn[row] = 1.0f / fmaxf(sqrtf(ss), EPSN);
    }
    __syncthreads();  // last barrier — K-loop below is barrier-free

    // ---- K-loop ----
    // A-frag pointers: wave h, frag mf -> r16 = h*5+mf; 1KB coalesced per load
    const unsigned short* apf[5];
#pragma unroll
    for (int mf = 0; mf < 5; ++mf)
        apf[mf] = Apack + ((size_t)(wave * 5 + mf) * NKT) * 512 + lane * 8;
    // B-frag LDS base: row g*16+lq, col quad*8 (+kt*32)
    const char* bb = reinterpret_cast<const char*>(Bs) + lq * (RSTRIDE * 2) + quad * 16;

    U16x4 aP[3][5];
    short8 bP[2][3];
    f32x4 acc[5][3];
#pragma unroll
    for (int mf = 0; mf < 5; ++mf)
#pragma unroll
        for (int g = 0; g < 3; ++g) acc[mf][g] = (f32x4)0.f;

#define LOADA(kt, slot)                                                           \
    _Pragma("unroll") for (int mf = 0; mf < 5; ++mf)                              \
        aP[slot][mf].u = *reinterpret_cast<const uint4*>(apf[mf] + (kt) * 512)
#define LOADB(kt, slot)                                                           \
    _Pragma("unroll") for (int g = 0; g < 3; ++g)                                 \
        bP[slot][g] = *reinterpret_cast<const short8*>(bb + g * 16 * (RSTRIDE * 2) + (kt) * 64)

    LOADA(0, 0);
    LOADA(1, 1);
    LOADB(0, 0);

#pragma unroll
    for (int kt = 0; kt < NKT; ++kt) {
        if (kt + 2 < NKT) { LOADA(kt + 2, (kt + 2) % 3); }
        if (kt + 1 < NKT) { LOADB(kt + 1, (kt + 1) & 1); }
#pragma unroll
        for (int mf = 0; mf < 5; ++mf)
#pragma unroll
            for (int g = 0; g < 3; ++g)
                acc[mf][g] = __builtin_amdgcn_mfma_f32_16x16x32_bf16(
                    aP[kt % 3][mf].s, bP[kt & 1][g], acc[mf][g], 0, 0, 0);
    }
#undef LOADA
#undef LOADB

    // ---- epilogue: per-session masked max, *invEn, store ----
#pragma unroll
    for (int g = 0; g < 3; ++g) {
        const int ncol = g * 16 + lq;
        const int n = n0 + ncol;
        const float inv_en = sInvEn[ncol];
#pragma unroll
        for (int bb4 = 0; bb4 < 4; ++bb4) {
            const int rLo = bb4 * S_;           // within the wave's 80 rows
            const int msk = sMask[wave * 4 + bb4];
            const int mfLo = rLo >> 4;
            const int mfHi = (rLo + S_ - 1) >> 4;
            float lm = -__builtin_inff();
#pragma unroll
            for (int mf = mfLo; mf <= mfHi; ++mf)
#pragma unroll
                for (int e = 0; e < 4; ++e) {
                    const int r = mf * 16 + quad * 4 + e;  // C/D: row=quad*4+e
                    const unsigned off = (unsigned)(r - rLo);
                    const bool ok = (off < (unsigned)S_) && ((msk >> off) & 1);
                    lm = ok ? fmaxf(lm, acc[mf][g][e]) : lm;
                }
            lm = fmaxf(lm, __shfl_xor(lm, 16, 64));
            lm = fmaxf(lm, __shfl_xor(lm, 32, 64));
            if (quad == 0 && n < NITEMS)
                out[(size_t)(wave * 4 + bb4) * NITEMS + n] = lm * inv_en;
        }
    }
}

extern "C" void kernel_launch(void* const* d_in, const int* in_sizes, int n_in,
                              void* d_out, int out_size, void* d_ws, size_t ws_size,
                              hipStream_t stream) {
    const float* hidden = (const float*)d_in[0];   // [16,1280,768] f32
    const float* emb    = (const float*)d_in[1];   // [50000,768] f32
    const int*   pos    = (const int*)d_in[3];     // [16,1280] i32
    float* out = (float*)d_out;                    // [16,50000] f32

    unsigned short* Apack = (unsigned short*)d_ws;                 // 20*24*512 bf16 = 480KB
    int* valid = (int*)((char*)d_ws + (size_t)20 * NKT * 512 * 2); // 320 ints

    pool_kernel<<<dim3(320), dim3(192), 0, stream>>>(hidden, pos, Apack, valid);
    gemm_kernel<<<dim3((NITEMS + BN - 1) / BN), dim3(256), 0, stream>>>(emb, Apack, valid, out);
}